// Round 3
// baseline (3624.126 us; speedup 1.0000x reference)
//
#include <hip/hip_runtime.h>
#include <cstdint>

// LSTM persistent kernel for MI355X (gfx950), round 3.
// B=256, T=1024, I=128, H=256, O=128. All inputs/outputs fp32.
//
// Grid: 256 WGs = 16 batch-groups x 16 column-tiles; one WG/CU (forced by LDS).
// Weights in registers as bf16 hi/lo MFMA B-fragments (bf16x3 split products).
// R3 change: self-validating h exchange. Each h element is a u64
// (tag<<32)|(lo_bf16<<16)|hi_bf16 stored with ONE relaxed agent-scope 8B
// atomic (write-through, L3-coherent). Readers poll the data words until all
// tags == t; the validated words are the operands. This removes the R2 chain
// (store drain -> flag store -> flag poll RT -> data load RT) and replaces it
// with: store one-way -> poll hit. No flags, no s_sleep, no extra barriers.
// WAR safety (2 parities): the overwriting store at iter t is after
// barrier(1), which follows all 4 waves' polls of tag t (collectively all 16
// peers); a peer posting tag t has -- via MFMA register dependence + its own
// barrier -- finished reading the h_{t-2} slab being overwritten.
// Poison 0xAAAAAAAA never equals an expected tag (1..1024): no false ready.

#define T_    1024
#define I_    128
#define H_    256

typedef short s8v __attribute__((ext_vector_type(8)));
typedef float f4v __attribute__((ext_vector_type(4)));
typedef unsigned short u16;
typedef unsigned int   u32;
typedef unsigned long long u64;

__device__ __forceinline__ u16 f2bf(float f) {
  union { float f; u32 u; } v; v.f = f;
  u32 r = v.u + 0x7FFFu + ((v.u >> 16) & 1u);
  return (u16)(r >> 16);
}
__device__ __forceinline__ float bf2f(u16 h) {
  union { u32 u; float f; } v; v.u = ((u32)h) << 16;
  return v.f;
}
__device__ __forceinline__ float sig_(float x)  { return 1.0f / (1.0f + __expf(-x)); }
__device__ __forceinline__ float tanh_(float x) { return 2.0f / (1.0f + __expf(-2.0f * x)) - 1.0f; }

// unpack 4 u64 (low 32 bits = (lo16<<16)|hi16 packed bf16 pair) -> hi/lo s8v
__device__ __forceinline__ void unpack4(const u64 w[4], s8v& hi, s8v& lo) {
  #pragma unroll
  for (int j = 0; j < 4; j++) {
    u32 d = (u32)w[j];
    hi[2*j]   = (short)(u16)d;
    lo[2*j]   = (short)(u16)(d >> 16);
    // elements are interleaved: each u64 holds ONE h element; pairs of u64
    // feed consecutive frag slots. w[j] covers frag slots {2j, 2j+1}? No --
    // one u64 = one element. 4 u64 = 4 elements -> half a frag. See caller.
    (void)0;
  }
}

__global__ __launch_bounds__(256, 1) void lstm_persist(
    const float* __restrict__ x, const float* __restrict__ Wih,
    const float* __restrict__ Whh, const float* __restrict__ bih,
    const float* __restrict__ bhh, const float* __restrict__ Wout,
    const float* __restrict__ bout, float* __restrict__ out,
    u64* __restrict__ hbuf)
{
  const int bid  = blockIdx.x;
  // XCD co-location heuristic (perf-only): group members share bid&7.
  const int xcd  = bid & 7;
  const int slot = bid >> 3;
  const int ct   = slot & 15;                 // column tile (0..15)
  const int g    = ((slot >> 4) << 3) | xcd;  // batch group (0..15)
  const int tid  = threadIdx.x;
  const int wave = tid >> 6;
  const int lane = tid & 63;
  const int lm   = lane & 15;   // MFMA m (A) / n (B) index
  const int lq   = lane >> 4;   // MFMA quad

  __shared__ u16   Wlds[2][64][392];        // setup W staging; reused for W_out
  __shared__ u16   xlds[2][2][16][136];     // [parity][hi/lo][m][k(128)+pad]
  __shared__ float partial[4][4][16][20];   // [wave][gate][m][hc+pad]

  // ---- stage W slice (concat Wih rows 0..127, Whh rows 128..383) col-major ----
  for (int it = tid; it < 384 * 64; it += 256) {
    int k = it >> 6;
    int c = it & 63;                              // gate = c>>4, n = c&15
    int gcol = (c >> 4) * 256 + ct * 16 + (c & 15);
    float w = (k < 128) ? Wih[k * 1024 + gcol] : Whh[(k - 128) * 1024 + gcol];
    u16 hi = f2bf(w);
    Wlds[0][c][k] = hi;
    Wlds[1][c][k] = f2bf(w - bf2f(hi));
  }
  __syncthreads();

  // ---- per-wave W fragments in registers: wave owns k-tiles {w, w+4, w+8} ----
  // B-frag layout (16x16x32): lane holds B[k = lq*8+j][n = lm], j=0..7.
  s8v wfrag[3][4][2];
  #pragma unroll
  for (int ki = 0; ki < 3; ki++) {
    const int kt = wave + 4 * ki;
    #pragma unroll
    for (int gg = 0; gg < 4; gg++) {
      #pragma unroll
      for (int p = 0; p < 2; p++)
        wfrag[ki][gg][p] = *(const s8v*)&Wlds[p][gg * 16 + lm][kt * 32 + lq * 8];
    }
  }
  __syncthreads();

  // cell-update thread mapping: one thread per (batch m, h-col)
  const int cm  = tid >> 4;
  const int chc = tid & 15;
  float biasv[4];
  #pragma unroll
  for (int gg = 0; gg < 4; gg++) {
    int col = gg * 256 + ct * 16 + chc;
    biasv[gg] = bih[col] + bhh[col];
  }
  float cstate = 0.0f;

  // x prefetch mapping: thread loads x[g*16+xr][t][xc0..xc0+7]
  const int xr  = tid >> 4;
  const int xc0 = (tid & 15) * 8;
  const float* xbase = x + (size_t)(g * 16 + xr) * (T_ * I_) + xc0;

  const size_t hpar   = (size_t)16 * 16 * 256;  // parity stride (u64 elems)
  const size_t hgbase = (size_t)g * 16 * 256;   // group base within parity

  auto xstore = [&](int par, float4 a, float4 b) {
    float v[8] = {a.x, a.y, a.z, a.w, b.x, b.y, b.z, b.w};
    union { u16 u[8]; s8v s; } hi, lo;
    #pragma unroll
    for (int j = 0; j < 8; j++) {
      u16 h = f2bf(v[j]);
      hi.u[j] = h;
      lo.u[j] = f2bf(v[j] - bf2f(h));
    }
    *(s8v*)&xlds[par][0][xr][xc0] = hi.s;
    *(s8v*)&xlds[par][1][xr][xc0] = lo.s;
  };

  { // x_0 into parity 0
    float4 a = *(const float4*)(xbase + 0);
    float4 b = *(const float4*)(xbase + 4);
    xstore(0, a, b);
  }
  __syncthreads();

  // this wave's h-slab pointer pieces (k = wave*32 + lq*8 + j, and +128)
  const size_t hoff = (size_t)lm * 256 + wave * 32 + lq * 8;

  for (int t = 0; t < T_; t++) {
    const int par = t & 1;
    const int pn  = (t + 1) & 1;

    // prefetch x_{t+1} (clamped; read-only data)
    const int tn = (t + 1 < T_) ? (t + 1) : t;
    float4 xa = *(const float4*)(xbase + (size_t)tn * I_);
    float4 xb = *(const float4*)(xbase + (size_t)tn * I_ + 4);

    f4v acc[4];
    #pragma unroll
    for (int gg = 0; gg < 4; gg++)
      #pragma unroll
      for (int r = 0; r < 4; r++) acc[gg][r] = 0.0f;

    // x-part MFMA (k-tile = wave), independent of peers -> runs before poll.
    {
      s8v axh = *(const s8v*)&xlds[par][0][lm][wave * 32 + lq * 8];
      s8v axl = *(const s8v*)&xlds[par][1][lm][wave * 32 + lq * 8];
      #pragma unroll
      for (int gg = 0; gg < 4; gg++) {
        acc[gg] = __builtin_amdgcn_mfma_f32_16x16x32_bf16(axh, wfrag[0][gg][0], acc[gg], 0, 0, 0);
        acc[gg] = __builtin_amdgcn_mfma_f32_16x16x32_bf16(axl, wfrag[0][gg][0], acc[gg], 0, 0, 0);
        acc[gg] = __builtin_amdgcn_mfma_f32_16x16x32_bf16(axh, wfrag[0][gg][1], acc[gg], 0, 0, 0);
      }
    }

    if (t > 0) {
      // fused poll+load: spin until all 8 of this lane's h_t words carry tag t.
      const u64* hp = hbuf + (size_t)par * hpar + hgbase + hoff;
      const u32 s = (u32)t;
      u64 w0[4], w1[4];
      while (true) {
        #pragma unroll
        for (int j = 0; j < 4; j++) {
          w0[j] = __hip_atomic_load(hp + j,       __ATOMIC_RELAXED, __HIP_MEMORY_SCOPE_AGENT);
          w1[j] = __hip_atomic_load(hp + 128 + j, __ATOMIC_RELAXED, __HIP_MEMORY_SCOPE_AGENT);
        }
        bool ok = true;
        #pragma unroll
        for (int j = 0; j < 4; j++)
          ok &= ((u32)(w0[j] >> 32) == s) & ((u32)(w1[j] >> 32) == s);
        if (__all(ok)) break;
      }

      #pragma unroll
      for (int ki = 1; ki < 3; ki++) {
        const u64* w = (ki == 1) ? w0 : w1;
        s8v ahh, ahl;
        #pragma unroll
        for (int j = 0; j < 4; j++) {
          u32 d = (u32)w[j];
          // each u64 holds ONE h element; frag wants 8 consecutive k.
          // consecutive k live in consecutive u64 -> w[j] is k=lq*8+? ...
          // we loaded 4 u64 = 4 elements but the frag needs 8. Load pairs:
          ahh[j] = 0; ahl[j] = 0; (void)d;
        }
        // (replaced below)
        (void)ahh; (void)ahl;
      }
      // --- actual fragment build: each lane needs 8 consecutive k elements,
      // i.e. 8 u64. w0/w1 above hold only 4 each... so load as u64x2 pairs:
      // RE-DO: w0 covers k=lq*8..lq*8+3? No -- hp+j strides 1 element (8B),
      // so w0[0..3] are k = lq*8 .. lq*8+3 and we still need +4..+7.
      // Handled by the second half loads below.
      {
        const u64* hp2 = hp + 4;
        u64 w0b[4], w1b[4];
        #pragma unroll
        for (int j = 0; j < 4; j++) {
          w0b[j] = __hip_atomic_load(hp2 + j,       __ATOMIC_RELAXED, __HIP_MEMORY_SCOPE_AGENT);
          w1b[j] = __hip_atomic_load(hp2 + 128 + j, __ATOMIC_RELAXED, __HIP_MEMORY_SCOPE_AGENT);
        }
        // tags of these words: same producers (peer ct' = k>>4; k..k+7 spans
        // within one 16-col tile since lq*8 aligned 8 | 16-aligned rows), so
        // validated tags on w0/w1 cover w0b/w1b's producers too? k=lq*8..+3
        // and +4..+7 are the SAME 16-col peer tile (lq*8 is 8-aligned inside
        // a 16 block) -> same producer WG, but NOT the same 8B word: a
        // producer's per-thread stores are independent. Must validate these
        // tags too.
        bool ok2;
        do {
          ok2 = true;
          #pragma unroll
          for (int j = 0; j < 4; j++)
            ok2 &= ((u32)(w0b[j] >> 32) == (u32)t) & ((u32)(w1b[j] >> 32) == (u32)t);
          if (!__all(ok2)) {
            #pragma unroll
            for (int j = 0; j < 4; j++) {
              w0b[j] = __hip_atomic_load(hp2 + j,       __ATOMIC_RELAXED, __HIP_MEMORY_SCOPE_AGENT);
              w1b[j] = __hip_atomic_load(hp2 + 128 + j, __ATOMIC_RELAXED, __HIP_MEMORY_SCOPE_AGENT);
            }
            ok2 = false;
          }
        } while (!__all(ok2));

        s8v ahh1, ahl1, ahh2, ahl2;
        #pragma unroll
        for (int j = 0; j < 4; j++) {
          u32 d0 = (u32)w0[j], d0b = (u32)w0b[j];
          u32 d1 = (u32)w1[j], d1b = (u32)w1b[j];
          ahh1[j]     = (short)(u16)d0;          ahl1[j]     = (short)(u16)(d0 >> 16);
          ahh1[j + 4] = (short)(u16)d0b;         ahl1[j + 4] = (short)(u16)(d0b >> 16);
          ahh2[j]     = (short)(u16)d1;          ahl2[j]     = (short)(u16)(d1 >> 16);
          ahh2[j + 4] = (short)(u16)d1b;         ahl2[j + 4] = (short)(u16)(d1b >> 16);
        }
        #pragma unroll
        for (int gg = 0; gg < 4; gg++) {
          acc[gg] = __builtin_amdgcn_mfma_f32_16x16x32_bf16(ahh1, wfrag[1][gg][0], acc[gg], 0, 0, 0);
          acc[gg] = __builtin_amdgcn_mfma_f32_16x16x32_bf16(ahl1, wfrag[1][gg][0], acc[gg], 0, 0, 0);
          acc[gg] = __builtin_amdgcn_mfma_f32_16x16x32_bf16(ahh1, wfrag[1][gg][1], acc[gg], 0, 0, 0);
          acc[gg] = __builtin_amdgcn_mfma_f32_16x16x32_bf16(ahh2, wfrag[2][gg][0], acc[gg], 0, 0, 0);
          acc[gg] = __builtin_amdgcn_mfma_f32_16x16x32_bf16(ahl2, wfrag[2][gg][0], acc[gg], 0, 0, 0);
          acc[gg] = __builtin_amdgcn_mfma_f32_16x16x32_bf16(ahh2, wfrag[2][gg][1], acc[gg], 0, 0, 0);
        }
      }
    }

    // write per-wave partial gates (C layout: col=lm, row=lq*4+r)
    #pragma unroll
    for (int gg = 0; gg < 4; gg++)
      #pragma unroll
      for (int r = 0; r < 4; r++)
        partial[wave][gg][lq * 4 + r][lm] = acc[gg][r];
    __syncthreads();   // barrier(1): also proves all waves finished their polls

    // cell update: thread (cm, chc)
    float ga = biasv[0], gb = biasv[1], gc = biasv[2], gd = biasv[3];
    #pragma unroll
    for (int w = 0; w < 4; w++) {
      ga += partial[w][0][cm][chc];
      gb += partial[w][1][cm][chc];
      gc += partial[w][2][cm][chc];
      gd += partial[w][3][cm][chc];
    }
    float i_t = sig_(ga), f_t = sig_(gb), g_t = tanh_(gc), o_t = sig_(gd);
    cstate = f_t * cstate + i_t * g_t;
    float h = o_t * tanh_(cstate);

    // publish h_{t+1}: one self-validating u64 (tag | packed hi/lo bf16)
    u16 hhi = f2bf(h);
    u16 hlo = f2bf(h - bf2f(hhi));
    u64 val = ((u64)(u32)(t + 1) << 32) | ((u32)hlo << 16) | (u32)hhi;
    u64* hw = hbuf + (size_t)pn * hpar + hgbase + (size_t)cm * 256 + ct * 16 + chc;
    __hip_atomic_store(hw, val, __ATOMIC_RELAXED, __HIP_MEMORY_SCOPE_AGENT);

    // convert x_{t+1} into the other parity's LDS planes
    xstore(pn, xa, xb);
    __syncthreads();   // barrier(2): xlds[pn] ready; partial[] reads done
  }

  // ---- output projection: out = h_T @ W_out + b_out ----
  // stage W_out cols [ct*8, ct*8+8) into Wlds[p][n][k], zero-pad n in [8,16)
  for (int it = tid; it < 16 * 256; it += 256) {
    int n = it >> 8;
    int k = it & 255;
    float w = (n < 8) ? Wout[k * 128 + ct * 8 + n] : 0.0f;
    u16 hi = f2bf(w);
    Wlds[0][n][k] = hi;
    Wlds[1][n][k] = f2bf(w - bf2f(hi));
  }
  __syncthreads();

  f4v oacc;
  #pragma unroll
  for (int r = 0; r < 4; r++) oacc[r] = 0.0f;
  const u64* hb0 = hbuf + hgbase;   // h_T (tag 1024) lives at parity 0
  #pragma unroll
  for (int ki = 0; ki < 2; ki++) {
    const int hk = (wave * 2 + ki) * 32 + lq * 8;
    const u64* hp = hb0 + (size_t)lm * 256 + hk;
    u64 w[8];
    bool ok;
    do {
      #pragma unroll
      for (int j = 0; j < 8; j++)
        w[j] = __hip_atomic_load(hp + j, __ATOMIC_RELAXED, __HIP_MEMORY_SCOPE_AGENT);
      ok = true;
      #pragma unroll
      for (int j = 0; j < 8; j++) ok &= ((u32)(w[j] >> 32) == (u32)T_);
    } while (!__all(ok));
    s8v ahh, ahl;
    #pragma unroll
    for (int j = 0; j < 8; j++) {
      u32 d = (u32)w[j];
      ahh[j] = (short)(u16)d;
      ahl[j] = (short)(u16)(d >> 16);
    }
    s8v bh  = *(const s8v*)&Wlds[0][lm][hk];
    s8v bl  = *(const s8v*)&Wlds[1][lm][hk];
    oacc = __builtin_amdgcn_mfma_f32_16x16x32_bf16(ahh, bh, oacc, 0, 0, 0);
    oacc = __builtin_amdgcn_mfma_f32_16x16x32_bf16(ahl, bh, oacc, 0, 0, 0);
    oacc = __builtin_amdgcn_mfma_f32_16x16x32_bf16(ahh, bl, oacc, 0, 0, 0);
  }
  #pragma unroll
  for (int r = 0; r < 4; r++) partial[wave][0][lq * 4 + r][lm] = oacc[r];
  __syncthreads();

  if (tid < 128) {
    int m  = tid >> 3;
    int oc = tid & 7;
    float v = bout[ct * 8 + oc];
    #pragma unroll
    for (int w = 0; w < 4; w++) v += partial[w][0][m][oc];
    out[(size_t)(g * 16 + m) * 128 + ct * 8 + oc] = v;
  }
}

extern "C" void kernel_launch(void* const* d_in, const int* in_sizes, int n_in,
                              void* d_out, int out_size, void* d_ws, size_t ws_size,
                              hipStream_t stream) {
  const float* x    = (const float*)d_in[0];
  const float* Wih  = (const float*)d_in[1];
  const float* Whh  = (const float*)d_in[2];
  const float* bih  = (const float*)d_in[3];
  const float* bhh  = (const float*)d_in[4];
  const float* Wout = (const float*)d_in[5];
  const float* bout = (const float*)d_in[6];
  float* out = (float*)d_out;

  // hbuf: 2 parities * 16 groups * 16 rows * 256 cols * 8 B = 1 MB of d_ws.
  u64* hbuf = (u64*)d_ws;

  hipLaunchKernelGGL(lstm_persist, dim3(256), dim3(256), 0, stream,
                     x, Wih, Whh, bih, bhh, Wout, bout, out, hbuf);
}